// Round 1
// baseline (212.371 us; speedup 1.0000x reference)
//
#include <hip/hip_runtime.h>

// Problem constants (from reference): B,T,L,R,E,F
#define B_ 8
#define T_ 16
#define L_ 128
#define R_ 1024
#define E_ 5
#define F_ 512

typedef short short8 __attribute__((ext_vector_type(8)));
typedef float floatx4 __attribute__((ext_vector_type(4)));

// fp32 -> bf16 bits, round-half-up (matches previously verified kernel)
__device__ __forceinline__ unsigned short f2bf(float f) {
  unsigned u = __float_as_uint(f);
  return (unsigned short)((u + 0x8000u) >> 16);
}

__device__ __forceinline__ short8 pack8(floatx4 lo, floatx4 hi) {
  short8 v;
  v[0] = (short)f2bf(lo[0]); v[1] = (short)f2bf(lo[1]);
  v[2] = (short)f2bf(lo[2]); v[3] = (short)f2bf(lo[3]);
  v[4] = (short)f2bf(hi[0]); v[5] = (short)f2bf(hi[1]);
  v[6] = (short)f2bf(hi[2]); v[7] = (short)f2bf(hi[3]);
  return v;
}

// async 16B global->LDS DMA; lane i's data lands at ldsbase + i*16
__device__ __forceinline__ void stage16(const float* g, float* lds) {
  __builtin_amdgcn_global_load_lds(
      (const __attribute__((address_space(1))) void*)g,
      (__attribute__((address_space(3))) void*)lds, 16, 0, 0);
}

// s_waitcnt immediates (gfx9 encoding): lgkmcnt=15 (don't care), expcnt=7,
// vmcnt in bits [3:0]
#define WAITCNT_VM3 0xF73   // vmcnt(3): this wave's current-chunk 3 DMAs done
#define WAITCNT_VM2 0xF72   // vmcnt(2): for waves that stage only 2/chunk
#define WAITCNT_VM0 0xF70   // vmcnt(0)

// ---------------------------------------------------------------------------
// Kernel 1: rot = QR(pre_rot).Q (LAPACK Householder convention), then
// new_lig[b,t,l,:] = rot[b,t] @ lig_coord[b,l] + trans[b,t].
// Also zeroes out[bt] so the fused kernel can atomicAdd.
// ---------------------------------------------------------------------------
__global__ void prep_kernel(const float* __restrict__ lig_coord,
                            const float* __restrict__ pre_rot,
                            const float* __restrict__ trans,
                            float* __restrict__ new_lig,
                            float* __restrict__ out) {
  int bt = blockIdx.x;
  __shared__ float Qs[3][3];
  if (threadIdx.x == 0) {
    out[bt] = 0.f;                      // zero output for atomic accumulation
    float a[3][3], q[3][3];
    #pragma unroll
    for (int i = 0; i < 3; ++i)
      #pragma unroll
      for (int j = 0; j < 3; ++j) {
        a[i][j] = pre_rot[(bt * 3 + i) * 3 + j];
        q[i][j] = (i == j) ? 1.f : 0.f;
      }
    for (int k = 0; k < 3; ++k) {
      float alpha = a[k][k];
      float xn2 = 0.f;
      for (int i = k + 1; i < 3; ++i) xn2 += a[i][k] * a[i][k];
      float nrm = sqrtf(alpha * alpha + xn2);
      if (xn2 > 0.f && nrm > 0.f) {
        float beta = (alpha >= 0.f) ? -nrm : nrm;
        float tau = (beta - alpha) / beta;
        float inv = 1.f / (alpha - beta);
        float v[3] = {0.f, 0.f, 0.f};
        v[k] = 1.f;
        for (int i = k + 1; i < 3; ++i) v[i] = a[i][k] * inv;
        for (int j = k; j < 3; ++j) {
          float w = 0.f;
          for (int i = k; i < 3; ++i) w += v[i] * a[i][j];
          w *= tau;
          for (int i = k; i < 3; ++i) a[i][j] -= w * v[i];
        }
        for (int i = 0; i < 3; ++i) {
          float w = 0.f;
          for (int j = k; j < 3; ++j) w += q[i][j] * v[j];
          w *= tau;
          for (int j = k; j < 3; ++j) q[i][j] -= w * v[j];
        }
      }
    }
    for (int i = 0; i < 3; ++i)
      for (int j = 0; j < 3; ++j) Qs[i][j] = q[i][j];
  }
  __syncthreads();
  int b = bt >> 4;
  int l = threadIdx.x;
  float cx = lig_coord[(b * L_ + l) * 3 + 0];
  float cy = lig_coord[(b * L_ + l) * 3 + 1];
  float cz = lig_coord[(b * L_ + l) * 3 + 2];
  float nx = Qs[0][0] * cx + Qs[0][1] * cy + Qs[0][2] * cz + trans[bt * 3 + 0];
  float ny = Qs[1][0] * cx + Qs[1][1] * cy + Qs[1][2] * cz + trans[bt * 3 + 1];
  float nz = Qs[2][0] * cx + Qs[2][1] * cy + Qs[2][2] * cz + trans[bt * 3 + 2];
  float* o = new_lig + ((size_t)bt * L_ + l) * 3;
  o[0] = nx; o[1] = ny; o[2] = nz;
}

// ---------------------------------------------------------------------------
// Kernel 2 (fused): per block (r-tile of 32, b):
//  Phase A: GEMM  atn[e][m][n] = sum_f lig[b,m,e,f]*rec[b,r0+n,e,f]
//           as ONE 80-chunk vmcnt-pipelined K-sweep (e,f contiguous in mem),
//           5 e-accumulators live in registers (never spilled to memory).
//  Phase B: mask acc by (m<ligN && r<recN); distance/power phase straight
//           from the MFMA C-fragment layout; block-reduce U[16]; atomicAdd.
// Tile: M=128 (all L) x N=32, 8 waves (wave tile 16x32), BK=32 f32, dbuf.
// ---------------------------------------------------------------------------
__launch_bounds__(512)
__global__ void fused_kernel(const float* __restrict__ lig_feat,
                             const float* __restrict__ rec_feat,
                             const float* __restrict__ rec_coord,
                             const int* __restrict__ lig_counts,
                             const int* __restrict__ rec_counts,
                             const float* __restrict__ new_lig,
                             float* __restrict__ out) {
  const int rt = blockIdx.x;          // 0..31
  const int b  = blockIdx.y;          // 0..7
  const int r0 = rt * 32;
  const int recN = rec_counts[b];
  if (r0 >= recN) return;             // fully-masked tile contributes 0

  // 40KB staging arena; reused for new_lig after GEMM (nl needs 24KB)
  __shared__ __align__(16) float smem[2 * 128 * 32 + 2 * 32 * 32];
  __shared__ float smr[8][T_];
  float* const As0 = smem;                // [2][128*32]
  float* const Bs0 = smem + 2 * 128 * 32; // [2][32*32]

  const int tid  = threadIdx.x;
  const int wave = tid >> 6;
  const int lane = tid & 63;
  const int lrow = lane & 15;
  const int quad = lane >> 4;
  const int wm   = wave * 16;

  // staging: each wave stages 2x8 A-rows; waves 0-3 also stage 8 B-rows.
  // 16B-chunk swizzle applied on the GLOBAL side (DMA LDS dst is linear).
  const int lr8 = lane >> 3;
  const int sw  = (lane & 7) ^ lr8;
  const bool bwave = (wave < 4);

  const float* ga[2];
  #pragma unroll
  for (int i = 0; i < 2; ++i) {
    int row = wave * 16 + i * 8 + lr8;
    ga[i] = lig_feat + ((size_t)(b * L_ + row) * E_) * F_ + sw * 4;
  }
  // address computed for all waves; only dereferenced when bwave
  const float* gb = rec_feat +
      ((size_t)(b * R_ + r0 + wave * 8 + lr8) * E_) * F_ + sw * 4;

  const int dstA0 = (wave * 16 + 0) * 32;
  const int dstA1 = (wave * 16 + 8) * 32;
  const int dstB  = (wave * 8) * 32;

  floatx4 acc[E_][2];
  #pragma unroll
  for (int e = 0; e < E_; ++e)
    #pragma unroll
    for (int j = 0; j < 2; ++j)
      acc[e][j] = (floatx4){0.f, 0.f, 0.f, 0.f};

  // prologue: chunk 0 -> buf 0
  stage16(ga[0], As0 + dstA0);
  stage16(ga[1], As0 + dstA1);
  if (bwave) stage16(gb, Bs0 + dstB);

  // fragment-read physical chunks (row&7 == lane&7 for all fragment rows)
  const int c0 = (2 * quad) ^ (lane & 7);

  // 80-chunk K-sweep: chunk g covers e=g>>4, f=(g&15)*32..+31 — contiguous
  // in memory, so the prefetch pipeline runs straight across e boundaries.
  #pragma unroll
  for (int e = 0; e < E_; ++e) {
    #pragma unroll 1
    for (int kc = 0; kc < 16; ++kc) {
      const int g = e * 16 + kc;
      const int cur = g & 1;
      if (g > 0)
        __builtin_amdgcn_s_barrier();   // all waves done reading buf[cur^1]
      if (g < 79) {                     // prefetch chunk g+1 -> buf[cur^1]
        const int col = (g + 1) * 32;
        stage16(ga[0] + col, As0 + (cur ^ 1) * (128 * 32) + dstA0);
        stage16(ga[1] + col, As0 + (cur ^ 1) * (128 * 32) + dstA1);
        if (bwave) {
          stage16(gb + col, Bs0 + (cur ^ 1) * (32 * 32) + dstB);
          __builtin_amdgcn_s_waitcnt(WAITCNT_VM3);  // chunk g landed; g+1 in flight
        } else {
          __builtin_amdgcn_s_waitcnt(WAITCNT_VM2);
        }
      } else {
        __builtin_amdgcn_s_waitcnt(WAITCNT_VM0);
      }
      __builtin_amdgcn_s_barrier();     // every wave's chunk-g stage landed
      __builtin_amdgcn_sched_barrier(0);

      const float* abase = As0 + cur * (128 * 32) + (wm + lrow) * 32;
      short8 af = pack8(*(const floatx4*)(abase + c0 * 4),
                        *(const floatx4*)(abase + (c0 ^ 1) * 4));
      const float* bbase0 = Bs0 + cur * (32 * 32) + (lrow) * 32;
      const float* bbase1 = Bs0 + cur * (32 * 32) + (16 + lrow) * 32;
      short8 bf0 = pack8(*(const floatx4*)(bbase0 + c0 * 4),
                         *(const floatx4*)(bbase0 + (c0 ^ 1) * 4));
      short8 bf1 = pack8(*(const floatx4*)(bbase1 + c0 * 4),
                         *(const floatx4*)(bbase1 + (c0 ^ 1) * 4));
      acc[e][0] = __builtin_amdgcn_mfma_f32_16x16x32_bf16(af, bf0, acc[e][0], 0, 0, 0);
      acc[e][1] = __builtin_amdgcn_mfma_f32_16x16x32_bf16(af, bf1, acc[e][1], 0, 0, 0);
    }
  }

  __syncthreads();                      // GEMM LDS traffic fully retired

  // ---- Phase B: distance/power, atn consumed straight from C-fragments ----
  // C layout (verified): m = wm + quad*4 + reg, n = j*16 + lrow.

  // stage new_lig[b] ([T,L,3] = 24KB) into reused staging LDS
  float* const nlp = smem;
  {
    const floatx4* src = (const floatx4*)(new_lig + (size_t)b * T_ * L_ * 3);
    floatx4* dst = (floatx4*)nlp;       // 6144 floats = 1536 float4 = 512*3
    #pragma unroll
    for (int i = 0; i < 3; ++i) dst[tid + i * 512] = src[tid + i * 512];
  }
  __syncthreads();

  // pair mask applied ONCE by zeroing acc registers (distance loop unmasked)
  const int ligN = lig_counts[b];
  #pragma unroll
  for (int j = 0; j < 2; ++j) {
    const bool nv = (r0 + j * 16 + lrow) < recN;
    #pragma unroll
    for (int reg = 0; reg < 4; ++reg) {
      const bool mv = (wm + quad * 4 + reg) < ligN;
      if (!(nv && mv)) {
        #pragma unroll
        for (int e = 0; e < E_; ++e) acc[e][j][reg] = 0.f;
      }
    }
  }

  float rcx[2], rcy[2], rcz[2];
  #pragma unroll
  for (int j = 0; j < 2; ++j) {
    const float* rp = rec_coord + (size_t)(b * R_ + r0 + j * 16 + lrow) * 3;
    rcx[j] = rp[0]; rcy[j] = rp[1]; rcz[j] = rp[2];
  }

  float u[T_];
  #pragma unroll
  for (int t = 0; t < T_; ++t) u[t] = 0.f;

  #pragma unroll
  for (int t = 0; t < T_; ++t) {        // full unroll: u[t] stays in regs
    float nx[4], ny[4], nz[4];
    #pragma unroll
    for (int reg = 0; reg < 4; ++reg) { // quad-uniform -> LDS broadcast
      const float* np = nlp + ((t * L_) + wm + quad * 4 + reg) * 3;
      nx[reg] = np[0]; ny[reg] = np[1]; nz[reg] = np[2];
    }
    #pragma unroll
    for (int j = 0; j < 2; ++j)
      #pragma unroll
      for (int reg = 0; reg < 4; ++reg) {
        float dx = nx[reg] - rcx[j];
        float dy = ny[reg] - rcy[j];
        float dz = nz[reg] - rcz[j];
        float d2 = fmaf(dx, dx, fmaf(dy, dy, dz * dz));
        d2 = fmaxf(d2, 1e-20f);
        float rs  = rsqrtf(d2);         // exps [-3,-2,-1,1,2]
        float rs2 = rs * rs;
        float rs3 = rs2 * rs;
        float d1  = d2 * rs;
        float c = acc[0][j][reg] * rs3;
        c = fmaf(acc[1][j][reg], rs2, c);
        c = fmaf(acc[2][j][reg], rs,  c);
        c = fmaf(acc[3][j][reg], d1,  c);
        c = fmaf(acc[4][j][reg], d2,  c);
        u[t] += c;
      }
  }

  // block-reduce U[16] and accumulate
  #pragma unroll
  for (int t = 0; t < T_; ++t) {
    float v = u[t];
    #pragma unroll
    for (int m = 32; m > 0; m >>= 1) v += __shfl_xor(v, m, 64);
    if (lane == 0) smr[wave][t] = v;
  }
  __syncthreads();
  if (tid < T_) {
    float s = 0.f;
    #pragma unroll
    for (int w = 0; w < 8; ++w) s += smr[w][tid];
    atomicAdd(&out[b * T_ + tid], s);
  }
}

// ---------------------------------------------------------------------------
extern "C" void kernel_launch(void* const* d_in, const int* in_sizes, int n_in,
                              void* d_out, int out_size, void* d_ws, size_t ws_size,
                              hipStream_t stream) {
  const float* lig_feat   = (const float*)d_in[0];
  const float* rec_feat   = (const float*)d_in[1];
  const float* lig_coord  = (const float*)d_in[2];
  const float* rec_coord  = (const float*)d_in[3];
  const float* pre_rot    = (const float*)d_in[4];
  const float* trans      = (const float*)d_in[5];
  const int*   lig_counts = (const int*)d_in[6];
  const int*   rec_counts = (const int*)d_in[7];
  float* out = (float*)d_out;

  // ws: new_lig [B,T,L,3] f32 (196KB) — only intermediate that remains
  float* new_lig = (float*)d_ws;

  prep_kernel<<<dim3(B_ * T_), dim3(L_), 0, stream>>>(lig_coord, pre_rot, trans,
                                                      new_lig, out);
  fused_kernel<<<dim3(R_ / 32, B_), dim3(512), 0, stream>>>(
      lig_feat, rec_feat, rec_coord, lig_counts, rec_counts, new_lig, out);
}